// Round 6
// baseline (140.647 us; speedup 1.0000x reference)
//
#include <hip/hip_runtime.h>
#include <math.h>

#define BLOCK 256

typedef float v2f __attribute__((ext_vector_type(2)));

// ---------------------------------------------------------------------------
// Pass A: pack refs into SoA-8 groups: per group of 8 refs, 32 floats:
// [x0..x7][y0..y7][z0..z7][w0..w7], w = r2 = (x*x + y*y) + z*z  (np op order).
// 128 B per group -> the scan's uniform reads merge into s_load_dwordx16.
// ---------------------------------------------------------------------------
__global__ __launch_bounds__(BLOCK) void prep_refs(
    const float* __restrict__ ref, float* __restrict__ soa, int Nr) {
#pragma clang fp contract(off)
    int j = blockIdx.x * BLOCK + threadIdx.x;
    if (j < Nr) {
        float x = ref[j * 3 + 0];
        float y = ref[j * 3 + 1];
        float z = ref[j * 3 + 2];
        float r2 = (x * x + y * y) + z * z;
        int g = j >> 3, r = j & 7;
        float* b = soa + (size_t)g * 32;
        b[r]      = x;
        b[8 + r]  = y;
        b[16 + r] = z;
        b[24 + r] = r2;
    }
}

// packed distance for 2 refs; per-half rounding identical to:
//   t = qx*rx; t = fmaf(qy,ry,t); t = fmaf(qz,rz,t);
//   a = q2 + rw; d = fmaf(-2, t, a)
// ref operands come straight from SGPR pairs (wave-uniform).
__device__ __forceinline__ v2f pkdist(v2f x, v2f y, v2f z, v2f w,
                                      v2f qxx, v2f qyy, v2f qzz,
                                      v2f q22, v2f m22) {
    v2f t, a;
    asm("v_pk_mul_f32 %0, %1, %2" : "=v"(t) : "s"(x), "v"(qxx));
    asm("v_pk_fma_f32 %0, %1, %2, %0" : "+v"(t) : "s"(y), "v"(qyy));
    asm("v_pk_fma_f32 %0, %1, %2, %0" : "+v"(t) : "s"(z), "v"(qzz));
    asm("v_pk_add_f32 %0, %1, %2" : "=v"(a) : "s"(w), "v"(q22));
    asm("v_pk_fma_f32 %0, %1, %2, %0" : "+v"(a) : "v"(m22), "v"(t));
    return a;  // unclamped d2 pair
}

// branchless top-3 insert; strict '<' + ascending j == jax top_k tie-break.
#define INSERT(dv, jv) do {                                         \
    float d_ = (dv); int j_ = (jv);                                 \
    bool c0 = d_ < e0, c1 = d_ < e1, c2 = d_ < e2;                  \
    int ni0 = c0 ? j_ : i0;                                         \
    int ni1 = c0 ? i0 : (c1 ? j_ : i1);                             \
    int ni2 = c1 ? i1 : (c2 ? j_ : i2);                             \
    float ne0 = fminf(d_, e0);                                      \
    float ne1 = __builtin_amdgcn_fmed3f(d_, e0, e1);                \
    float ne2 = __builtin_amdgcn_fmed3f(d_, e1, e2);                \
    e0 = ne0; e1 = ne1; e2 = ne2; i0 = ni0; i1 = ni1; i2 = ni2;     \
} while (0)

// ---------------------------------------------------------------------------
// Pass B: one thread = one query (64 queries/wave). Ref group index is
// wave-uniform -> refs arrive via batched s_load_dwordx16 into SGPRs and are
// consumed by VOP3P directly (no per-lane VMEM, no per-lane RF replication —
// the measured R2-R5 bottleneck). Clamp max(d2,0) deferred to survivors
// (R4/R5-proven). chunkRefs is a multiple of 8.
// ---------------------------------------------------------------------------
__global__ __launch_bounds__(BLOCK, 8) void knn_scan(
    const float* __restrict__ qpts, const float* __restrict__ soa,
    float* __restrict__ cd, int* __restrict__ ci,
    int Nq, int Nr, int chunkRefs) {
#pragma clang fp contract(off)
    int qi = blockIdx.x * BLOCK + threadIdx.x;
    int c  = blockIdx.y;
    int jbeg = c * chunkRefs;
    int jend = jbeg + chunkRefs;
    if (jend > Nr) jend = Nr;

    float qx = 0.f, qy = 0.f, qz = 0.f;
    if (qi < Nq) {
        qx = qpts[qi * 3 + 0];
        qy = qpts[qi * 3 + 1];
        qz = qpts[qi * 3 + 2];
    }
    float q2 = (qx * qx + qy * qy) + qz * qz;

    v2f qxx = {qx, qx}, qyy = {qy, qy}, qzz = {qz, qz};
    v2f q22 = {q2, q2}, m22 = {-2.0f, -2.0f};

    const float FINF = __builtin_inff();
    float e0 = FINF, e1 = FINF, e2 = FINF;
    int   i0 = 0x7fffffff, i1 = 0x7fffffff, i2 = 0x7fffffff;

    int nref  = jend - jbeg;
    if (nref < 0) nref = 0;
    int nfull = nref >> 3;
    int gbeg  = jbeg >> 3;               // jbeg is a multiple of 8

#pragma unroll 2
    for (int g = 0; g < nfull; ++g) {
        const float* b = soa + (size_t)(gbeg + g) * 32;  // uniform pointer
        int jb = jbeg + g * 8;                           // uniform (SGPR)
        v2f x01 = *(const v2f*)(b + 0),  x23 = *(const v2f*)(b + 2);
        v2f x45 = *(const v2f*)(b + 4),  x67 = *(const v2f*)(b + 6);
        v2f y01 = *(const v2f*)(b + 8),  y23 = *(const v2f*)(b + 10);
        v2f y45 = *(const v2f*)(b + 12), y67 = *(const v2f*)(b + 14);
        v2f z01 = *(const v2f*)(b + 16), z23 = *(const v2f*)(b + 18);
        v2f z45 = *(const v2f*)(b + 20), z67 = *(const v2f*)(b + 22);
        v2f w01 = *(const v2f*)(b + 24), w23 = *(const v2f*)(b + 26);
        v2f w45 = *(const v2f*)(b + 28), w67 = *(const v2f*)(b + 30);

        v2f d01 = pkdist(x01, y01, z01, w01, qxx, qyy, qzz, q22, m22);
        v2f d23 = pkdist(x23, y23, z23, w23, qxx, qyy, qzz, q22, m22);
        v2f d45 = pkdist(x45, y45, z45, w45, qxx, qyy, qzz, q22, m22);
        v2f d67 = pkdist(x67, y67, z67, w67, qxx, qyy, qzz, q22, m22);

        INSERT(d01.x, jb + 0); INSERT(d01.y, jb + 1);
        INSERT(d23.x, jb + 2); INSERT(d23.y, jb + 3);
        INSERT(d45.x, jb + 4); INSERT(d45.y, jb + 5);
        INSERT(d67.x, jb + 6); INSERT(d67.y, jb + 7);
    }

    // tail (Nr % 8): scalar, same rounding order
    for (int j = jbeg + nfull * 8; j < jend; ++j) {
        const float* b = soa + (size_t)(j >> 3) * 32;
        int r = j & 7;
        float x = b[r], y = b[8 + r], z = b[16 + r], w = b[24 + r];
        float t = qx * x;
        t = fmaf(qy, y, t);
        t = fmaf(qz, z, t);
        float a = q2 + w;
        float d = fmaf(-2.0f, t, a);
        INSERT(d, j);
    }

    // clamp survivors to match reference max(d2, 0)
    e0 = fmaxf(e0, 0.0f);
    e1 = fmaxf(e1, 0.0f);
    e2 = fmaxf(e2, 0.0f);

    if (qi < Nq) {
        size_t base = (size_t)(c * 3) * (size_t)Nq + (size_t)qi; // [c][slot][q]
        cd[base]                 = e0;
        cd[base + (size_t)Nq]    = e1;
        cd[base + 2*(size_t)Nq]  = e2;
        ci[base]                 = i0;
        ci[base + (size_t)Nq]    = i1;
        ci[base + 2*(size_t)Nq]  = i2;
    }
}

// ---------------------------------------------------------------------------
// Pass C: merge nCand candidates per query. Candidate stream is (chunk asc,
// slot asc) == ascending ref index for equal distances, and within-chunk
// slots are (d asc, idx asc) — so strict '<' insertion reproduces the full
// lexicographic (d, idx) top-3 == jax top_k. Then weights/gather in
// reference op order.
// ---------------------------------------------------------------------------
__global__ __launch_bounds__(BLOCK) void knn_finish(
    const float* __restrict__ flow, const float* __restrict__ cd,
    const int* __restrict__ ci, float* __restrict__ out,
    int Nq, int nCand) {
#pragma clang fp contract(off)
    int qi = blockIdx.x * BLOCK + threadIdx.x;
    if (qi >= Nq) return;

    const float FINF = __builtin_inff();
    float bd0 = FINF, bd1 = FINF, bd2 = FINF;
    int   bi0 = 0x7fffffff, bi1 = 0x7fffffff, bi2 = 0x7fffffff;

    for (int s = 0; s < nCand; ++s) {
        float d  = cd[(size_t)s * (size_t)Nq + (size_t)qi];
        int   ix = ci[(size_t)s * (size_t)Nq + (size_t)qi];
        bool c0 = d < bd0;
        bool c1 = d < bd1;
        bool c2 = d < bd2;
        int ni0 = c0 ? ix : bi0;
        int ni1 = c0 ? bi0 : (c1 ? ix : bi1);
        int ni2 = c1 ? bi1 : (c2 ? ix : bi2);
        float nd0 = fminf(d, bd0);
        float nd1 = __builtin_amdgcn_fmed3f(d, bd0, bd1);
        float nd2 = __builtin_amdgcn_fmed3f(d, bd1, bd2);
        bd0 = nd0; bd1 = nd1; bd2 = nd2;
        bi0 = ni0; bi1 = ni1; bi2 = ni2;
    }

    float s0 = sqrtf(bd0);
    float s1 = sqrtf(bd1);
    float s2 = sqrtf(bd2);
    float w0 = 1.0f / (s0 + 1e-8f);
    float w1 = 1.0f / (s1 + 1e-8f);
    float w2 = 1.0f / (s2 + 1e-8f);
    float wsum = (w0 + w1) + w2;
    w0 = w0 / wsum;
    w1 = w1 / wsum;
    w2 = w2 / wsum;

    float f0x = flow[bi0 * 3 + 0], f0y = flow[bi0 * 3 + 1], f0z = flow[bi0 * 3 + 2];
    float f1x = flow[bi1 * 3 + 0], f1y = flow[bi1 * 3 + 1], f1z = flow[bi1 * 3 + 2];
    float f2x = flow[bi2 * 3 + 0], f2y = flow[bi2 * 3 + 1], f2z = flow[bi2 * 3 + 2];

    out[qi * 3 + 0] = (w0 * f0x + w1 * f1x) + w2 * f2x;
    out[qi * 3 + 1] = (w0 * f0y + w1 * f1y) + w2 * f2y;
    out[qi * 3 + 2] = (w0 * f0z + w1 * f1z) + w2 * f2z;
}

extern "C" void kernel_launch(void* const* d_in, const int* in_sizes, int n_in,
                              void* d_out, int out_size, void* d_ws, size_t ws_size,
                              hipStream_t stream) {
    const float* q    = (const float*)d_in[0];
    const float* ref  = (const float*)d_in[1];
    const float* flow = (const float*)d_in[2];
    float* out = (float*)d_out;

    int Nq = in_sizes[0] / 3;
    int Nr = in_sizes[1] / 3;

    int nGroups = (Nr + 7) / 8;
    size_t soaBytes = (size_t)nGroups * 32 * sizeof(float);

    // chunks: 32 fills 256 CUs at 8 blocks/CU; halve if ws too small.
    int chunks = 32;
    while (chunks > 4) {
        size_t need = soaBytes
                    + (size_t)chunks * 3 * (size_t)Nq * (sizeof(float) + sizeof(int));
        if (need <= ws_size) break;
        chunks >>= 1;
    }

    char* ws = (char*)d_ws;
    float* soa = (float*)ws;
    size_t off = soaBytes;
    float* cd = (float*)(ws + off);
    off += (size_t)chunks * 3 * (size_t)Nq * sizeof(float);
    int* ci = (int*)(ws + off);

    // chunkRefs: multiple of 8 so every chunk starts on a group boundary
    int chunkRefs = ((Nr + chunks - 1) / chunks + 7) & ~7;

    prep_refs<<<(Nr + BLOCK - 1) / BLOCK, BLOCK, 0, stream>>>(ref, soa, Nr);

    dim3 grid((Nq + BLOCK - 1) / BLOCK, chunks);
    knn_scan<<<grid, BLOCK, 0, stream>>>(q, soa, cd, ci, Nq, Nr, chunkRefs);

    knn_finish<<<(Nq + BLOCK - 1) / BLOCK, BLOCK, 0, stream>>>(
        flow, cd, ci, out, Nq, chunks * 3);
}

// Round 7
// 131.513 us; speedup vs baseline: 1.0695x; 1.0695x over previous
//
#include <hip/hip_runtime.h>
#include <math.h>

#define BLOCK 256
#define TILE  512   // refs per LDS tile: 64 SoA-8 groups = 8 KB

typedef float v2f __attribute__((ext_vector_type(2)));

// ---------------------------------------------------------------------------
// Pass A: SoA-8 groups: per 8 refs, 32 floats [x0..x7][y0..y7][z0..z7][w0..w7],
// w = r2 = (x*x + y*y) + z*z (np op order). Padded to a TILE multiple with
// (0,0,0,+INF): d = fma(-2, 0, q2+INF) = +INF, never selected by strict '<'.
// ---------------------------------------------------------------------------
__global__ __launch_bounds__(BLOCK) void prep_refs(
    const float* __restrict__ ref, float* __restrict__ soa, int Nr, int Npad) {
#pragma clang fp contract(off)
    int j = blockIdx.x * BLOCK + threadIdx.x;
    if (j < Npad) {
        float x = 0.f, y = 0.f, z = 0.f, r2;
        if (j < Nr) {
            x = ref[j * 3 + 0];
            y = ref[j * 3 + 1];
            z = ref[j * 3 + 2];
            r2 = (x * x + y * y) + z * z;
        } else {
            r2 = __builtin_inff();
        }
        int g = j >> 3, r = j & 7;
        float* b = soa + (size_t)g * 32;
        b[r]      = x;
        b[8 + r]  = y;
        b[16 + r] = z;
        b[24 + r] = r2;
    }
}

// packed distance for 2 refs; per-half rounding identical to the proven
//   t = qx*rx; t = fmaf(qy,ry,t); t = fmaf(qz,rz,t); a = q2+rw; d = fmaf(-2,t,a)
__device__ __forceinline__ v2f pkdist(v2f x, v2f y, v2f z, v2f w,
                                      v2f qxx, v2f qyy, v2f qzz,
                                      v2f q22, v2f m22) {
    v2f t, a;
    asm("v_pk_mul_f32 %0, %1, %2" : "=v"(t) : "v"(x), "v"(qxx));
    asm("v_pk_fma_f32 %0, %1, %2, %0" : "+v"(t) : "v"(y), "v"(qyy));
    asm("v_pk_fma_f32 %0, %1, %2, %0" : "+v"(t) : "v"(z), "v"(qzz));
    asm("v_pk_add_f32 %0, %1, %2" : "=v"(a) : "v"(w), "v"(q22));
    asm("v_pk_fma_f32 %0, %1, %2, %0" : "+v"(a) : "v"(m22), "v"(t));
    return a;  // unclamped d2 pair
}

// branchless top-3 insert; strict '<' + ascending j == jax top_k tie-break.
#define INSERT(dv, jv) do {                                         \
    float d_ = (dv); int j_ = (jv);                                 \
    bool c0 = d_ < e0, c1 = d_ < e1, c2 = d_ < e2;                  \
    int ni0 = c0 ? j_ : i0;                                         \
    int ni1 = c0 ? i0 : (c1 ? j_ : i1);                             \
    int ni2 = c1 ? i1 : (c2 ? j_ : i2);                             \
    float ne0 = fminf(d_, e0);                                      \
    float ne1 = __builtin_amdgcn_fmed3f(d_, e0, e1);                \
    float ne2 = __builtin_amdgcn_fmed3f(d_, e1, e2);                \
    e0 = ne0; e1 = ne1; e2 = ne2; i0 = ni0; i1 = ni1; i2 = ni2;     \
} while (0)

// ---------------------------------------------------------------------------
// Pass B: one thread = one query. Refs delivered via LDS (staged coalesced,
// then uniform-address broadcast ds_reads — in-order counted lgkmcnt, so the
// compiler pipelines them under the VALU; no scalar wait-all stalls, no
// per-lane VMEM replication — the R2-R6 walls).
// ---------------------------------------------------------------------------
__global__ __launch_bounds__(BLOCK, 4) void knn_scan(
    const float* __restrict__ qpts, const float4* __restrict__ soa4,
    float* __restrict__ cd, int* __restrict__ ci,
    int Nq, int chunkRefs, int Npad) {
#pragma clang fp contract(off)
    __shared__ float4 sref[TILE];   // TILE refs * 16 B = 8 KB

    int qi = blockIdx.x * BLOCK + threadIdx.x;
    int c  = blockIdx.y;
    int jbeg = c * chunkRefs;
    int jend = jbeg + chunkRefs;
    if (jend > Npad) jend = Npad;

    float qx = 0.f, qy = 0.f, qz = 0.f;
    if (qi < Nq) {
        qx = qpts[qi * 3 + 0];
        qy = qpts[qi * 3 + 1];
        qz = qpts[qi * 3 + 2];
    }
    float q2 = (qx * qx + qy * qy) + qz * qz;

    v2f qxx = {qx, qx}, qyy = {qy, qy}, qzz = {qz, qz};
    v2f q22 = {q2, q2}, m22 = {-2.0f, -2.0f};

    const float FINF = __builtin_inff();
    float e0 = FINF, e1 = FINF, e2 = FINF;
    int   i0 = 0x7fffffff, i1 = 0x7fffffff, i2 = 0x7fffffff;

    for (int tb = jbeg; tb < jend; tb += TILE) {
        // stage TILE refs (TILE float4s) coalesced; all threads participate
        const float4* src = soa4 + (size_t)tb;   // 1 float4 per ref in SoA-8
#pragma unroll
        for (int k = 0; k < TILE / BLOCK; ++k)
            sref[threadIdx.x + k * BLOCK] = src[threadIdx.x + k * BLOCK];
        __syncthreads();

        const float* base = (const float*)sref;
#pragma unroll 2
        for (int g = 0; g < TILE / 8; ++g) {
            const float* bb = base + g * 32;     // one SoA-8 group
            int jb = tb + g * 8;
            v2f x01 = *(const v2f*)(bb + 0),  x23 = *(const v2f*)(bb + 2);
            v2f x45 = *(const v2f*)(bb + 4),  x67 = *(const v2f*)(bb + 6);
            v2f y01 = *(const v2f*)(bb + 8),  y23 = *(const v2f*)(bb + 10);
            v2f y45 = *(const v2f*)(bb + 12), y67 = *(const v2f*)(bb + 14);
            v2f z01 = *(const v2f*)(bb + 16), z23 = *(const v2f*)(bb + 18);
            v2f z45 = *(const v2f*)(bb + 20), z67 = *(const v2f*)(bb + 22);
            v2f w01 = *(const v2f*)(bb + 24), w23 = *(const v2f*)(bb + 26);
            v2f w45 = *(const v2f*)(bb + 28), w67 = *(const v2f*)(bb + 30);

            v2f d01 = pkdist(x01, y01, z01, w01, qxx, qyy, qzz, q22, m22);
            v2f d23 = pkdist(x23, y23, z23, w23, qxx, qyy, qzz, q22, m22);
            v2f d45 = pkdist(x45, y45, z45, w45, qxx, qyy, qzz, q22, m22);
            v2f d67 = pkdist(x67, y67, z67, w67, qxx, qyy, qzz, q22, m22);

            INSERT(d01.x, jb + 0); INSERT(d01.y, jb + 1);
            INSERT(d23.x, jb + 2); INSERT(d23.y, jb + 3);
            INSERT(d45.x, jb + 4); INSERT(d45.y, jb + 5);
            INSERT(d67.x, jb + 6); INSERT(d67.y, jb + 7);
        }
        __syncthreads();   // safe to restage next tile
    }

    // clamp survivors to match reference max(d2, 0)
    e0 = fmaxf(e0, 0.0f);
    e1 = fmaxf(e1, 0.0f);
    e2 = fmaxf(e2, 0.0f);

    if (qi < Nq) {
        size_t base = (size_t)(c * 3) * (size_t)Nq + (size_t)qi; // [c][slot][q]
        cd[base]                 = e0;
        cd[base + (size_t)Nq]    = e1;
        cd[base + 2*(size_t)Nq]  = e2;
        ci[base]                 = i0;
        ci[base + (size_t)Nq]    = i1;
        ci[base + 2*(size_t)Nq]  = i2;
    }
}

// ---------------------------------------------------------------------------
// Pass C: merge nCand candidates per query. Candidate stream is (chunk asc,
// slot asc) == ascending ref index for equal distances, and within-chunk
// slots are (d asc, idx asc) — so strict '<' insertion reproduces the full
// lexicographic (d, idx) top-3 == jax top_k. Then weights/gather in
// reference op order.
// ---------------------------------------------------------------------------
__global__ __launch_bounds__(BLOCK) void knn_finish(
    const float* __restrict__ flow, const float* __restrict__ cd,
    const int* __restrict__ ci, float* __restrict__ out,
    int Nq, int nCand) {
#pragma clang fp contract(off)
    int qi = blockIdx.x * BLOCK + threadIdx.x;
    if (qi >= Nq) return;

    const float FINF = __builtin_inff();
    float bd0 = FINF, bd1 = FINF, bd2 = FINF;
    int   bi0 = 0x7fffffff, bi1 = 0x7fffffff, bi2 = 0x7fffffff;

    for (int s = 0; s < nCand; ++s) {
        float d  = cd[(size_t)s * (size_t)Nq + (size_t)qi];
        int   ix = ci[(size_t)s * (size_t)Nq + (size_t)qi];
        bool c0 = d < bd0;
        bool c1 = d < bd1;
        bool c2 = d < bd2;
        int ni0 = c0 ? ix : bi0;
        int ni1 = c0 ? bi0 : (c1 ? ix : bi1);
        int ni2 = c1 ? bi1 : (c2 ? ix : bi2);
        float nd0 = fminf(d, bd0);
        float nd1 = __builtin_amdgcn_fmed3f(d, bd0, bd1);
        float nd2 = __builtin_amdgcn_fmed3f(d, bd1, bd2);
        bd0 = nd0; bd1 = nd1; bd2 = nd2;
        bi0 = ni0; bi1 = ni1; bi2 = ni2;
    }

    float s0 = sqrtf(bd0);
    float s1 = sqrtf(bd1);
    float s2 = sqrtf(bd2);
    float w0 = 1.0f / (s0 + 1e-8f);
    float w1 = 1.0f / (s1 + 1e-8f);
    float w2 = 1.0f / (s2 + 1e-8f);
    float wsum = (w0 + w1) + w2;
    w0 = w0 / wsum;
    w1 = w1 / wsum;
    w2 = w2 / wsum;

    float f0x = flow[bi0 * 3 + 0], f0y = flow[bi0 * 3 + 1], f0z = flow[bi0 * 3 + 2];
    float f1x = flow[bi1 * 3 + 0], f1y = flow[bi1 * 3 + 1], f1z = flow[bi1 * 3 + 2];
    float f2x = flow[bi2 * 3 + 0], f2y = flow[bi2 * 3 + 1], f2z = flow[bi2 * 3 + 2];

    out[qi * 3 + 0] = (w0 * f0x + w1 * f1x) + w2 * f2x;
    out[qi * 3 + 1] = (w0 * f0y + w1 * f1y) + w2 * f2y;
    out[qi * 3 + 2] = (w0 * f0z + w1 * f1z) + w2 * f2z;
}

extern "C" void kernel_launch(void* const* d_in, const int* in_sizes, int n_in,
                              void* d_out, int out_size, void* d_ws, size_t ws_size,
                              hipStream_t stream) {
    const float* q    = (const float*)d_in[0];
    const float* ref  = (const float*)d_in[1];
    const float* flow = (const float*)d_in[2];
    float* out = (float*)d_out;

    int Nq = in_sizes[0] / 3;
    int Nr = in_sizes[1] / 3;

    int nTiles = (Nr + TILE - 1) / TILE;
    int Npad   = nTiles * TILE;
    size_t soaBytes = (size_t)Npad * 16;

    // chunks: one TILE per chunk if ws allows (32 for Nr=16384); halve on
    // ws pressure — chunkRefs stays a multiple of TILE (block loops tiles).
    int chunks = nTiles;
    while (chunks > 1) {
        size_t need = soaBytes
                    + (size_t)chunks * 3 * (size_t)Nq * (sizeof(float) + sizeof(int));
        if (need <= ws_size) break;
        chunks = (chunks + 1) >> 1;
    }
    int chunkTiles = (nTiles + chunks - 1) / chunks;
    int chunkRefs  = chunkTiles * TILE;
    int chunksEff  = (Npad + chunkRefs - 1) / chunkRefs;

    char* ws = (char*)d_ws;
    float* soa = (float*)ws;
    size_t off = soaBytes;
    float* cd = (float*)(ws + off);
    off += (size_t)chunksEff * 3 * (size_t)Nq * sizeof(float);
    int* ci = (int*)(ws + off);

    prep_refs<<<(Npad + BLOCK - 1) / BLOCK, BLOCK, 0, stream>>>(ref, soa, Nr, Npad);

    dim3 grid((Nq + BLOCK - 1) / BLOCK, chunksEff);
    knn_scan<<<grid, BLOCK, 0, stream>>>(q, (const float4*)soa, cd, ci,
                                         Nq, chunkRefs, Npad);

    knn_finish<<<(Nq + BLOCK - 1) / BLOCK, BLOCK, 0, stream>>>(
        flow, cd, ci, out, Nq, chunksEff * 3);
}